// Round 10
// baseline (78.901 us; speedup 1.0000x reference)
//
#include <hip/hip_runtime.h>

#define B_   4
#define CIN  23
#define H_   256
#define W_   512
#define CO   64
#define HC   16                  // h-chunks of 16
#define NPART (B_ * W_ * CO)     // 131072 floats per h-chunk partial

typedef float f32x4 __attribute__((ext_vector_type(4)));
typedef _Float16 half8 __attribute__((ext_vector_type(8)));
typedef unsigned int u32;
typedef u32 u32x4 __attribute__((ext_vector_type(4)));

// ---------------------------------------------------------------------------
// Kernel A: conv(23->64)+bias+relu, partial h-sum via MFMA (16x16x32 f16).
// Grid (wq=8, hc=16, b=4) = 512 blocks x 256 thr (4 waves).
// Block tile: 64 w x 16 h x ALL 64 co -> msa read ONCE chip-wide, full
// 128B lines, 256B-coalesced staging loads (lane = w).
// LDS: xs[h-slot][k-pair][64 w] packed half2 words; write bank = lane%32
// (2-way free); read uses (w + 4p)&63 add-swizzle -> kg-groups on disjoint
// banks (2-way free). Each B-frag feeds 4 MFMAs (4 co-group A-frags).
// Frag layout (verified r8): A lane=(m=l&15, k=8*(l>>4)+j), B lane=
// (n=l&15, k=8*(l>>4)+j), C lane=(m=4*(l>>4)+r, n=l&15).
// ---------------------------------------------------------------------------
__global__ __launch_bounds__(256) void conv_mfma_kernel(
    const float* __restrict__ msa,   // [B][CIN][H][W]
    const float* __restrict__ Wc,    // [CO][CIN]
    const float* __restrict__ bias,  // [CO]
    float* __restrict__ partial)     // [HC][B][W][CO]
{
    const int tid  = threadIdx.x;
    const int lane = tid & 63;
    const int wv   = tid >> 6;        // wave: staging h-slot / compute w-group
    const int wrow = lane & 15;
    const int kg   = lane >> 4;       // 0..3

    const int wq = blockIdx.x;        // 0..7
    const int hc = blockIdx.y;        // 0..15
    const int b  = blockIdx.z;
    const int w0 = wq * 64;

    // A fragments: afrag[g][j] = W[16g + wrow][8kg + j], zero-padded k>=23
    half8 afrag[4];
#pragma unroll
    for (int g = 0; g < 4; ++g)
#pragma unroll
        for (int j = 0; j < 8; ++j) {
            const int k = 8 * kg + j;
            afrag[g][j] = (_Float16)((k < CIN) ? Wc[(16 * g + wrow) * CIN + k] : 0.f);
        }
    // bias for this lane's C rows: co = 16g + 4kg + r
    float br[4][4];
#pragma unroll
    for (int g = 0; g < 4; ++g)
#pragma unroll
        for (int r = 0; r < 4; ++r) br[g][r] = bias[16 * g + 4 * kg + r];

    f32x4 acc[4];
#pragma unroll
    for (int g = 0; g < 4; ++g) acc[g] = (f32x4){0.f, 0.f, 0.f, 0.f};

    __shared__ u32 xs[4][12][64];     // 12 KiB: [h-slot][k-pair][w-slot]

    const size_t HW = (size_t)H_ * W_;

    for (int s = 0; s < 4; ++s) {
        // ---- stage: wave wv stages h-slot wv (h = hc*16 + s*4 + wv) ----
        {
            const int h = hc * 16 + s * 4 + wv;
            const float* src = msa + ((size_t)b * CIN) * HW + (size_t)h * W_ + w0 + lane;
#pragma unroll
            for (int p = 0; p < 12; ++p) {
                const float lo = src[(size_t)(2 * p) * HW];
                const float hi = (2 * p + 1 < CIN) ? src[(size_t)(2 * p + 1) * HW] : 0.f;
                xs[wv][p][(lane + 4 * p) & 63] =
                    __builtin_bit_cast(u32, __builtin_amdgcn_cvt_pkrtz(lo, hi));
            }
        }
        __syncthreads();
        // ---- compute: wave wv owns w-group [16wv, 16wv+16) ----
        const int wl = 16 * wv + wrow;     // w within block tile
#pragma unroll
        for (int hh = 0; hh < 4; ++hh) {
            u32x4 bw;
#pragma unroll
            for (int q = 0; q < 4; ++q) {
                const int p = 4 * kg + q;
                bw[q] = xs[hh][p][(wl + 4 * p) & 63];
            }
            const half8 bfrag = __builtin_bit_cast(half8, bw);
#pragma unroll
            for (int g = 0; g < 4; ++g) {
                f32x4 c = {0.f, 0.f, 0.f, 0.f};
                c = __builtin_amdgcn_mfma_f32_16x16x32_f16(afrag[g], bfrag, c, 0, 0, 0);
#pragma unroll
                for (int r = 0; r < 4; ++r)
                    acc[g][r] += fmaxf(c[r] + br[g][r], 0.f);
            }
        }
        __syncthreads();
    }

    // store: w = w0 + 16wv + wrow ; co base = 16g + 4kg ; 1KB/wave/g contiguous
    float* dst = partial + (((size_t)hc * B_ + b) * W_ + w0 + 16 * wv + wrow) * CO + 4 * kg;
#pragma unroll
    for (int g = 0; g < 4; ++g)
        *(f32x4*)(dst + 16 * g) = acc[g];
}

// ---------------------------------------------------------------------------
// Kernel B: avg[b][w][c] = (1/H) * sum_hc partial[hc][b][w][c]   (float4-wide)
// ---------------------------------------------------------------------------
__global__ __launch_bounds__(256) void reduce_avg_kernel(
    const float* __restrict__ partial,  // [HC][B][W][CO]
    float* __restrict__ avg)            // [B][W][CO]
{
    const int idx = blockIdx.x * 256 + threadIdx.x;   // f32x4 index, 0..32767
    const f32x4* p4 = (const f32x4*)partial;
    f32x4 s = p4[idx];
#pragma unroll
    for (int k = 1; k < HC; ++k) s += p4[(size_t)k * (NPART / 4) + idx];
    ((f32x4*)avg)[idx] = s * (1.0f / H_);
}

// ---------------------------------------------------------------------------
// Kernel C: out[b][wi][wj][c] = avg[b][wi][c] + avg[b][wj][c]
// Grid (wi=512, b=4) x 256 thr; each wave stores 1 KiB contiguous per iter.
// ---------------------------------------------------------------------------
__global__ __launch_bounds__(256) void pairs_kernel(
    const float* __restrict__ avg,  // [B][W][CO]
    float* __restrict__ out)        // [B][W][W][CO]
{
    const int b   = blockIdx.y;
    const int wi  = blockIdx.x;
    const int tid = threadIdx.x;
    const int cq  = tid & 15;   // c-quad (64 c = 16 float4)
    const int wj0 = tid >> 4;   // 0..15

    const f32x4* a4 = (const f32x4*)avg;
    const f32x4 aI = a4[(b * W_ + wi) * 16 + cq];
    f32x4* o4 = (f32x4*)out + ((size_t)(b * W_ + wi)) * W_ * 16;

#pragma unroll 4
    for (int wj = wj0; wj < W_; wj += 16) {
        const f32x4 aJ = a4[(b * W_ + wj) * 16 + cq];
        const f32x4 r = aI + aJ;
        __builtin_nontemporal_store(r, o4 + (size_t)wj * 16 + cq);
    }
}

extern "C" void kernel_launch(void* const* d_in, const int* in_sizes, int n_in,
                              void* d_out, int out_size, void* d_ws, size_t ws_size,
                              hipStream_t stream) {
    const float* msa = (const float*)d_in[0];   // (4, 23, 256, 512)
    const float* Wc  = (const float*)d_in[1];   // (64, 23)
    const float* bc  = (const float*)d_in[2];   // (64,)
    float* out = (float*)d_out;                 // (4, 512, 512, 64)
    float* avg = (float*)d_ws;                  // (4, 512, 64) = 512 KB scratch

    // partial[16][4][512][64] = 8 MiB staged in d_out; fully overwritten by
    // pairs_kernel afterwards (stream-ordered A -> B -> C).
    float* partial = (float*)d_out;

    conv_mfma_kernel<<<dim3(8, HC, B_), 256, 0, stream>>>(msa, Wc, bc, partial);
    reduce_avg_kernel<<<dim3(NPART / 4 / 256), 256, 0, stream>>>(partial, avg);
    pairs_kernel<<<dim3(W_, B_), 256, 0, stream>>>(avg, out);
}